// Round 9
// baseline (161.208 us; speedup 1.0000x reference)
//
#include <hip/hip_runtime.h>
#include <hip/hip_bf16.h>

#define DM 1024
#define NH 16
#define DK 64
#define TT 2048
#define NBATCH 4
#define BT 8192   // NBATCH*TT

typedef __attribute__((ext_vector_type(8))) short short8;
typedef __attribute__((ext_vector_type(4))) float f32x4;
typedef unsigned short u16;

#define MFMA(a,b,c) __builtin_amdgcn_mfma_f32_16x16x32_bf16((a),(b),(c),0,0,0)

// 1/sqrt(64) * log2(e): folded into Q so attn softmax can use exp2 directly
#define QSCALE 0.18033688011112684f

// raw v_exp_f32 (flush-denorm fine for softmax), skips OCML fixup code
#define EXP2(x) __builtin_amdgcn_exp2f(x)

__device__ __forceinline__ u16 f2bf(float f){
  union { float f; unsigned u; } v; v.f = f;
  return (u16)((v.u + 0x7fffu + ((v.u >> 16) & 1u)) >> 16);
}

__device__ __forceinline__ unsigned cvtpk(float lo, float hi){
  unsigned r;
  asm("v_cvt_pk_bf16_f32 %0, %1, %2" : "=v"(r) : "v"(lo), "v"(hi));
  return r;
}

// async global->LDS DMA, 16B/lane. LDS dest must be wave-uniform base (+lane*16).
__device__ __forceinline__ void gload16(const void* g, void* l){
  __builtin_amdgcn_global_load_lds((__attribute__((address_space(1))) void*)(g),
                                   (__attribute__((address_space(3))) void*)(l), 16, 0, 0);
}

// cross-lane reduce over the 4 16-lane groups (lane ^16, ^32): pure-VALU permlanes
__device__ __forceinline__ float plmax(float x){
#if __has_builtin(__builtin_amdgcn_permlane16_swap) && __has_builtin(__builtin_amdgcn_permlane32_swap)
  auto r = __builtin_amdgcn_permlane16_swap(__float_as_uint(x), __float_as_uint(x), false, false);
  x = fmaxf(__uint_as_float(r[0]), __uint_as_float(r[1]));
  auto r2 = __builtin_amdgcn_permlane32_swap(__float_as_uint(x), __float_as_uint(x), false, false);
  x = fmaxf(__uint_as_float(r2[0]), __uint_as_float(r2[1]));
#else
  x = fmaxf(x, __shfl_xor(x, 16, 64));
  x = fmaxf(x, __shfl_xor(x, 32, 64));
#endif
  return x;
}

__device__ __forceinline__ float plsum(float x){
#if __has_builtin(__builtin_amdgcn_permlane16_swap) && __has_builtin(__builtin_amdgcn_permlane32_swap)
  auto r = __builtin_amdgcn_permlane16_swap(__float_as_uint(x), __float_as_uint(x), false, false);
  x = __uint_as_float(r[0]) + __uint_as_float(r[1]);
  auto r2 = __builtin_amdgcn_permlane32_swap(__float_as_uint(x), __float_as_uint(x), false, false);
  x = __uint_as_float(r2[0]) + __uint_as_float(r2[1]);
#else
  x = x + __shfl_xor(x, 16, 64);
  x = x + __shfl_xor(x, 32, 64);
#endif
  return x;
}

// ---------------- x fp32 -> bf16 ----------------
__global__ __launch_bounds__(256) void cvt_x(const float* __restrict__ x, u16* __restrict__ xb){
  int i = (blockIdx.x * 256 + threadIdx.x) * 4;
  float4 v = *(const float4*)(x + i);
  u16 o0 = f2bf(v.x), o1 = f2bf(v.y), o2 = f2bf(v.z), o3 = f2bf(v.w);
  ushort4 o; o.x=o0; o.y=o1; o.z=o2; o.w=o3;
  *(ushort4*)(xb + i) = o;
}

// ---------------- W (K,N) fp32 -> wt (N,K) bf16, all 3 mats in one launch ----------------
__global__ __launch_bounds__(256) void twp(
    const float* __restrict__ Wq, const float* __restrict__ Wk, const float* __restrict__ Wv,
    u16* __restrict__ wtq, u16* __restrict__ wtk, u16* __restrict__ wtv){
  const float* W = (blockIdx.z == 0) ? Wq : (blockIdx.z == 1) ? Wk : Wv;
  u16* wt = (blockIdx.z == 0) ? wtq : (blockIdx.z == 1) ? wtk : wtv;
  __shared__ float tile[32][33];
  int k0 = blockIdx.x * 32, n0 = blockIdx.y * 32;
  int tx = threadIdx.x & 31, ty = threadIdx.x >> 5;
  #pragma unroll
  for(int r = ty; r < 32; r += 8)
    tile[r][tx] = W[(size_t)(k0 + r) * DM + n0 + tx];
  __syncthreads();
  #pragma unroll
  for(int r = ty; r < 32; r += 8)
    wt[(size_t)(n0 + r) * DM + k0 + tx] = f2bf(tile[tx][r]);
}

// ---------------- QKV projection GEMM (R6-verified 2-phase dbuf, ~72us) ----------------
// 128x128 tile, 4 waves; global_load_lds staging (linear dest, inverse-swizzled
// source); double-buffered: prefetch t+1 issued after the barrier, drained at the
// NEXT barrier. XCD-locality 1-D grid. V^T store KEY-PERMUTED (attn 16x16 PV
// consumes kappa order: key 16*hi+4*g+r -> pos 8*g+4*hi+r, within-64B relabel).
__global__ __launch_bounds__(256) void qkv_gemm(
    const u16* __restrict__ xb,
    const u16* __restrict__ wtq, const u16* __restrict__ wtk, const u16* __restrict__ wtv,
    const float* __restrict__ bq, const float* __restrict__ bk, const float* __restrict__ bv,
    u16* __restrict__ qws, u16* __restrict__ kws, u16* __restrict__ vtws){
  __shared__ u16 sa[2][128 * 64];
  __shared__ u16 sb[2][128 * 64];
  const int id = blockIdx.x;              // 0..1535
  const int idx = id >> 3;                // 0..191 within XCD
  const int mt = (id & 7) * 8 + (idx & 7);// M-tile 0..63
  const int y  = idx >> 3;                // weight panel 0..23
  const int m0 = mt * 128;
  const int ng = y * 128;
  const int mat = ng >> 10;
  const int n0 = ng & 1023;
  const u16* wt = (mat == 0) ? wtq : (mat == 1) ? wtk : wtv;
  const float* bias = (mat == 0) ? bq : (mat == 1) ? bk : bv;
  const int tid = threadIdx.x;
  const int lane = tid & 63, w = tid >> 6;
  const int wm = (w >> 1) * 64, wn = (w & 1) * 64;
  const int wbase0 = tid & 192;   // w*64, wave-uniform

  f32x4 acc[4][4] = {};

  // stage K-tile 0 -> buf 0 (async DMA)
  #pragma unroll
  for(int p = 0; p < 4; p++){
    int base = p * 256 + wbase0;
    int idx2 = base + lane;
    int row = idx2 >> 3;
    int chs = (idx2 & 7) ^ (row & 7);
    gload16(xb + (size_t)(m0 + row) * 1024 + chs * 8, (char*)sa[0] + base * 16);
    gload16(wt + (size_t)(n0 + row) * 1024 + chs * 8, (char*)sb[0] + base * 16);
  }

  #pragma unroll 1
  for(int kt = 0; kt < 16; kt++){
    const int cur = kt & 1;
    __syncthreads();               // drains vmcnt: buf[cur] ready; buf[cur^1] readers done

    if(kt + 1 < 16){
      const int k0n = (kt + 1) * 64;
      #pragma unroll
      for(int p = 0; p < 4; p++){
        int base = p * 256 + wbase0;
        int idx2 = base + lane;
        int row = idx2 >> 3;
        int chs = (idx2 & 7) ^ (row & 7);
        gload16(xb + (size_t)(m0 + row) * 1024 + k0n + chs * 8, (char*)sa[cur ^ 1] + base * 16);
        gload16(wt + (size_t)(n0 + row) * 1024 + k0n + chs * 8, (char*)sb[cur ^ 1] + base * 16);
      }
    }

    #pragma unroll
    for(int ks = 0; ks < 2; ks++){
      short8 af[4], bfr[4];
      #pragma unroll
      for(int i = 0; i < 4; i++){
        int ra = wm + i * 16 + (lane & 15);
        int ca = ks * 64 + (lane >> 4) * 16;
        af[i] = *(const short8*)((const char*)sa[cur] + ra * 128 + (ca ^ ((ra & 7) << 4)));
        int rb = wn + i * 16 + (lane & 15);
        bfr[i] = *(const short8*)((const char*)sb[cur] + rb * 128 + (ca ^ ((rb & 7) << 4)));
      }
      __builtin_amdgcn_s_setprio(1);
      #pragma unroll
      for(int i = 0; i < 4; i++)
        #pragma unroll
        for(int j = 0; j < 4; j++)
          acc[i][j] = MFMA(af[i], bfr[j], acc[i][j]);
      __builtin_amdgcn_s_setprio(0);
    }
  }

  const float scl = (mat == 0) ? QSCALE : 1.0f;
  #pragma unroll
  for(int j = 0; j < 4; j++){
    int n = n0 + wn + j * 16 + (lane & 15);
    float bv_ = bias[n];
    int h = n >> 6, d = n & 63;
    #pragma unroll
    for(int i = 0; i < 4; i++){
      int mb = m0 + wm + i * 16 + (lane >> 4) * 4;
      int b = mb >> 11, t = mb & 2047;
      int bh = b * NH + h;
      if(mat == 2){
        // V^T store, KEY-PERMUTED within each 32-key group (attn PV b128 reads)
        ushort4 o4;
        o4.x = f2bf(acc[i][j][0] + bv_);
        o4.y = f2bf(acc[i][j][1] + bv_);
        o4.z = f2bf(acc[i][j][2] + bv_);
        o4.w = f2bf(acc[i][j][3] + bv_);
        int tp = (t & ~31) | (((t >> 2) & 3) << 3) | (((t >> 4) & 1) << 2);
        *(ushort4*)(vtws + ((size_t)bh * DK + d) * TT + tp) = o4;
      } else {
        u16* dst = (mat == 0) ? qws : kws;
        #pragma unroll
        for(int r = 0; r < 4; r++){
          u16 o = f2bf((acc[i][j][r] + bv_) * scl);
          dst[((size_t)bh * TT + t + r) * DK + d] = o;
        }
      }
    }
  }
}

// ---------------- flash attention: 16x16 core, dual q-subtile register reuse ----------------
// R6-verified datapath (layouts, softmax, T12 pack, key-permuted V^T — conflict-free,
// 60us) with ONE new mechanism: each wave owns TWO 16-row q-subtiles (A at +0,
// B at +64) and every kfr/av LDS load feeds BOTH (2 MFMAs per load) -> LDS reads
// per q-row HALVE (kernel LDS traffic 2.79 -> 1.67 GB) with bit-identical
// addressing. 4-wave/128-row blocks, grid 1024 (4 blocks/CU x 4 waves = 16
// waves/CU, same as R6 — R8 lesson: the win condition is >=16 waves/CU).
// Longest-first within each XCD (qt descending) smooths the unpaired lengths.
// Sub-A skips the block's last k-tile (fully masked; wave-uniform doA); A masks
// diagonal at tile 2qt, B at 2qt+1. VGPR ~114 — under the 128 cliff.
__global__ __launch_bounds__(256) void attn(
    const u16* __restrict__ qws, const u16* __restrict__ kws, const u16* __restrict__ vtws,
    float* __restrict__ out){
  __shared__ u16 kt[2][64 * 64];    // [buf][key][d]  swizzled
  __shared__ u16 vt[2][64 * 64];    // [buf][d][key-permuted]  swizzled

  const int id = blockIdx.x;                // 0..1023
  const int xcd = id & 7, local = id >> 3;  // local 0..127
  const int qt = 15 - (local >> 3);         // longest-first within XCD
  const int bh = xcd * 8 + (local & 7);     // XCD k owns bh in [8k,8k+8)

  const int tid = threadIdx.x, lane = tid & 63, w = tid >> 6;   // w 0..3
  const int g = lane >> 4, ln = lane & 15;
  const int b = bh >> 4, h = bh & 15;
  const u16* kbase = kws + (size_t)bh * TT * DK;
  const u16* vbase = vtws + (size_t)bh * DK * TT;

  const int qA = qt * 128 + w * 16 + ln;    // sub-tile A q row
  const int qB = qA + 64;                   // sub-tile B q row

  // Q fragments (B-operand; pre-scaled by QSCALE): k-slots d = g*8+j (+32)
  short8 qfA[2], qfB[2];
  {
    const u16* gq = qws + ((size_t)bh * TT + qA) * DK + g * 8;
    qfA[0] = *(const short8*)gq;
    qfA[1] = *(const short8*)(gq + 32);
    const u16* gq2 = qws + ((size_t)bh * TT + qB) * DK + g * 8;
    qfB[0] = *(const short8*)gq2;
    qfB[1] = *(const short8*)(gq2 + 32);
  }

  f32x4 oA[4] = {}, oB[4] = {};
  float mA = -INFINITY, lA = 0.f;
  float mB = -INFINITY, lB = 0.f;

  const int nkt = 2 * qt + 2;               // block-level 64-key tiles

  // stage k-tile 0 -> buf 0 (async DMA; 256 threads x 2 passes cover 64x64)
  #pragma unroll
  for(int p = 0; p < 2; p++){
    int base = p * 256 + (tid & 192);
    int ci = base + lane, row = ci >> 3, chs = (ci & 7) ^ (row & 7);
    gload16(kbase + (size_t)row * DK + chs * 8, (char*)kt[0] + base * 16);
    gload16(vbase + (size_t)row * TT + chs * 8, (char*)vt[0] + base * 16);
  }

  #pragma unroll 1
  for(int kti = 0; kti < nkt; kti++){
    const int cur = kti & 1;
    __syncthreads();               // buf[cur] ready; buf[cur^1] readers done

    if(kti + 1 < nkt){             // prefetch next tile into buf[cur^1]
      const int k0n = (kti + 1) * 64;
      #pragma unroll
      for(int p = 0; p < 2; p++){
        int base = p * 256 + (tid & 192);
        int ci = base + lane, row = ci >> 3, chs = (ci & 7) ^ (row & 7);
        gload16(kbase + (size_t)(k0n + row) * DK + chs * 8, (char*)kt[cur ^ 1] + base * 16);
        gload16(vbase + (size_t)row * TT + k0n + chs * 8, (char*)vt[cur ^ 1] + base * 16);
      }
    }

    const bool doA = (kti < nkt - 1);   // wave-uniform: A's last tile is nkt-2

    // S^T = K Q : each kfr load feeds BOTH sub-tiles
    f32x4 sA[4], sB[4];
    __builtin_amdgcn_s_setprio(1);
    #pragma unroll
    for(int i = 0; i < 4; i++){
      f32x4 cA = {}, cB = {};
      #pragma unroll
      for(int ks = 0; ks < 2; ks++){
        int rb = i * 16 + ln;
        int cb = ks * 64 + g * 16;
        short8 kfr = *(const short8*)((const char*)kt[cur] + rb * 128 + (cb ^ ((rb & 7) << 4)));
        if(doA) cA = MFMA(kfr, qfA[ks], cA);
        cB = MFMA(kfr, qfB[ks], cB);
      }
      sA[i] = cA; sB[i] = cB;
    }
    __builtin_amdgcn_s_setprio(0);

    const int k0 = kti * 64;
    if(doA && kti == nkt - 2){     // A diagonal tile
      #pragma unroll
      for(int i = 0; i < 4; i++)
        #pragma unroll
        for(int r = 0; r < 4; r++)
          if(k0 + i * 16 + g * 4 + r > qA) sA[i][r] = -INFINITY;
    }
    if(kti == nkt - 1){            // B diagonal tile
      #pragma unroll
      for(int i = 0; i < 4; i++)
        #pragma unroll
        for(int r = 0; r < 4; r++)
          if(k0 + i * 16 + g * 4 + r > qB) sB[i][r] = -INFINITY;
    }

    union PU { short8 s8; unsigned u[4]; };
    PU pbA[2], pbB[2];

    // ----- softmax + pack, sub-tile A (wave-uniform guard) -----
    if(doA){
      float mx0 = fmaxf(fmaxf(sA[0][0], sA[0][1]), fmaxf(sA[0][2], sA[0][3]));
      float mx1 = fmaxf(fmaxf(sA[1][0], sA[1][1]), fmaxf(sA[1][2], sA[1][3]));
      float mx2 = fmaxf(fmaxf(sA[2][0], sA[2][1]), fmaxf(sA[2][2], sA[2][3]));
      float mx3 = fmaxf(fmaxf(sA[3][0], sA[3][1]), fmaxf(sA[3][2], sA[3][3]));
      float pmax = plmax(fmaxf(fmaxf(mx0, mx1), fmaxf(mx2, mx3)));
      if(!__all(pmax <= mA + 8.f)){
        float mnew = fmaxf(mA, pmax);
        float alpha = EXP2(mA - mnew);
        lA *= alpha;
        #pragma unroll
        for(int i = 0; i < 4; i++)
          #pragma unroll
          for(int r = 0; r < 4; r++) oA[i][r] *= alpha;
        mA = mnew;
      }
      #pragma unroll
      for(int i = 0; i < 4; i++)
        #pragma unroll
        for(int r = 0; r < 4; r++){
          float p = EXP2(sA[i][r] - mA);
          sA[i][r] = p; lA += p;
        }
      #pragma unroll
      for(int ks = 0; ks < 2; ks++){
        pbA[ks].u[0] = cvtpk(sA[2*ks][0],   sA[2*ks][1]);
        pbA[ks].u[1] = cvtpk(sA[2*ks][2],   sA[2*ks][3]);
        pbA[ks].u[2] = cvtpk(sA[2*ks+1][0], sA[2*ks+1][1]);
        pbA[ks].u[3] = cvtpk(sA[2*ks+1][2], sA[2*ks+1][3]);
      }
    }

    // ----- softmax + pack, sub-tile B -----
    {
      float mx0 = fmaxf(fmaxf(sB[0][0], sB[0][1]), fmaxf(sB[0][2], sB[0][3]));
      float mx1 = fmaxf(fmaxf(sB[1][0], sB[1][1]), fmaxf(sB[1][2], sB[1][3]));
      float mx2 = fmaxf(fmaxf(sB[2][0], sB[2][1]), fmaxf(sB[2][2], sB[2][3]));
      float mx3 = fmaxf(fmaxf(sB[3][0], sB[3][1]), fmaxf(sB[3][2], sB[3][3]));
      float pmax = plmax(fmaxf(fmaxf(mx0, mx1), fmaxf(mx2, mx3)));
      if(!__all(pmax <= mB + 8.f)){
        float mnew = fmaxf(mB, pmax);
        float alpha = EXP2(mB - mnew);
        lB *= alpha;
        #pragma unroll
        for(int i = 0; i < 4; i++)
          #pragma unroll
          for(int r = 0; r < 4; r++) oB[i][r] *= alpha;
        mB = mnew;
      }
      #pragma unroll
      for(int i = 0; i < 4; i++)
        #pragma unroll
        for(int r = 0; r < 4; r++){
          float p = EXP2(sB[i][r] - mB);
          sB[i][r] = p; lB += p;
        }
      #pragma unroll
      for(int ks = 0; ks < 2; ks++){
        pbB[ks].u[0] = cvtpk(sB[2*ks][0],   sB[2*ks][1]);
        pbB[ks].u[1] = cvtpk(sB[2*ks][2],   sB[2*ks][3]);
        pbB[ks].u[2] = cvtpk(sB[2*ks+1][0], sB[2*ks+1][1]);
        pbB[ks].u[3] = cvtpk(sB[2*ks+1][2], sB[2*ks+1][3]);
      }
    }

    // O^T += V^T P^T : each av load feeds BOTH sub-tiles
    __builtin_amdgcn_s_setprio(1);
    #pragma unroll
    for(int i = 0; i < 4; i++){
      int dr = i * 16 + ln;
      const char* vrow = (const char*)vt[cur] + dr * 128;
      int sw = (dr & 7) << 4;
      #pragma unroll
      for(int ks = 0; ks < 2; ks++){
        short8 av = *(const short8*)(vrow + ((64 * ks + g * 16) ^ sw));
        if(doA) oA[i] = MFMA(av, pbA[ks].s8, oA[i]);
        oB[i] = MFMA(av, pbB[ks].s8, oB[i]);
      }
    }
    __builtin_amdgcn_s_setprio(0);
  }

  // epilogue x2: deferred l reduce, then float4 stores (d = i*16 + g*4 + r)
  lA = plsum(lA);
  lB = plsum(lB);
  float invA = 1.0f / lA, invB = 1.0f / lB;
  float* orowA = out + ((size_t)(b * TT + qA)) * DM + h * 64 + g * 4;
  float* orowB = out + ((size_t)(b * TT + qB)) * DM + h * 64 + g * 4;
  #pragma unroll
  for(int i = 0; i < 4; i++){
    float4 v4;
    v4.x = oA[i][0] * invA; v4.y = oA[i][1] * invA;
    v4.z = oA[i][2] * invA; v4.w = oA[i][3] * invA;
    *(float4*)(orowA + i * 16) = v4;
    float4 v5;
    v5.x = oB[i][0] * invB; v5.y = oB[i][1] * invB;
    v5.z = oB[i][2] * invB; v5.w = oB[i][3] * invB;
    *(float4*)(orowB + i * 16) = v5;
  }
}

extern "C" void kernel_launch(void* const* d_in, const int* in_sizes, int n_in,
                              void* d_out, int out_size, void* d_ws, size_t ws_size,
                              hipStream_t stream){
  const float* x  = (const float*)d_in[0];
  const float* Wq = (const float*)d_in[1];
  const float* bq = (const float*)d_in[2];
  const float* Wk = (const float*)d_in[3];
  const float* bk = (const float*)d_in[4];
  const float* Wv = (const float*)d_in[5];
  const float* bv = (const float*)d_in[6];
  float* out = (float*)d_out;

  char* ws = (char*)d_ws;
  u16* xb   = (u16*)(ws);                       // 16 MB  x bf16 (M,K)
  u16* wtq  = (u16*)(ws + (16u << 20));         //  2 MB  Wq^T bf16 (N,K)
  u16* wtk  = (u16*)(ws + (18u << 20));
  u16* wtv  = (u16*)(ws + (20u << 20));
  u16* qws  = (u16*)(ws + (22u << 20));         // 16 MB  Q (BH,T,DK) bf16 (pre-scaled)
  u16* kws  = (u16*)(ws + (38u << 20));         // 16 MB  K (BH,T,DK) bf16
  u16* vtws = (u16*)(ws + (54u << 20));         // 16 MB  V^T (BH,DK,T) bf16, key-permuted

  cvt_x<<<dim3(BT * DM / 1024), dim3(256), 0, stream>>>(x, xb);
  twp<<<dim3(32, 32, 3), dim3(256), 0, stream>>>(Wq, Wk, Wv, wtq, wtk, wtv);
  qkv_gemm<<<dim3(1536), dim3(256), 0, stream>>>(xb, wtq, wtk, wtv, bq, bk, bv, qws, kws, vtws);
  attn<<<dim3(1024), dim3(256), 0, stream>>>(qws, kws, vtws, out);
}